// Round 15
// baseline (324.044 us; speedup 1.0000x reference)
//
#include <hip/hip_runtime.h>
#include <hip/hip_bf16.h>

#define BN_EPS 1e-5f
#define CAPB 6144   // bucket slack capacity; mean load 4337, +27 sigma
#define LOG2E 1.4426950408889634f

typedef unsigned short ushort_t;
typedef __attribute__((ext_vector_type(2))) float f32x2;
typedef __attribute__((ext_vector_type(4))) float f32x4v;
typedef __attribute__((ext_vector_type(8))) short short8;

__device__ __forceinline__ float blo(unsigned w) { unsigned t = w << 16; return __builtin_bit_cast(float, t); }
__device__ __forceinline__ float bhi(unsigned w) { unsigned t = w & 0xffff0000u; return __builtin_bit_cast(float, t); }
__device__ __forceinline__ ushort_t bfbits(float a) {
  return (ushort_t)__builtin_bit_cast(unsigned short, __float2bfloat16(a));
}
__device__ __forceinline__ unsigned packbf2(float a, float b) {
  unsigned lo = (unsigned)bfbits(a);
  unsigned hi = (unsigned)bfbits(b);
  return lo | (hi << 16);
}
__device__ __forceinline__ float fexp2(float x) {
#if __has_builtin(__builtin_amdgcn_exp2f)
  return __builtin_amdgcn_exp2f(x);
#else
  return exp2f(x);
#endif
}
__device__ __forceinline__ void pkfma(f32x2& d, f32x2 a, f32x2 b) {
  asm("v_pk_fma_f32 %0, %1, %2, %0" : "+v"(d) : "v"(a), "v"(b));
}

// ---------------- CSR build: bucketed two-pass, coalesced ----------------
// key = (dst<<16)|src  (both < 65536). bin = dst>>8.

__global__ __launch_bounds__(256) void k_bucket(const int* __restrict__ ei, int E, int etot,
                                                unsigned* __restrict__ bkt, int* __restrict__ gCur,
                                                int nb) {
  __shared__ int sm[256];
  __shared__ int lstart[256];
  __shared__ int lcur[256];
  __shared__ int gbase[256];
  __shared__ unsigned stage[1024];
  int tid = threadIdx.x;
  int base = blockIdx.x * 1024;
  int cnt = etot - base; if (cnt > 1024) cnt = 1024;

  sm[tid] = 0;
  __syncthreads();
  unsigned key[4]; int have[4];
  #pragma unroll
  for (int u = 0; u < 4; ++u) {
    int idx = tid + u * 256;
    have[u] = (idx < cnt);
    if (have[u]) {
      int i = base + idx;
      int s, d;
      if (i < E) { s = ei[i]; d = ei[E + i]; }
      else       { s = i - E; d = s; }
      unsigned k = ((unsigned)d << 16) | (unsigned)s;
      key[u] = k;
      atomicAdd(&sm[k >> 24], 1);
    }
  }
  __syncthreads();
  int myc = sm[tid];
  #pragma unroll
  for (int off = 1; off < 256; off <<= 1) {
    int t = sm[tid];
    int u = (tid >= off) ? sm[tid - off] : 0;
    __syncthreads();
    sm[tid] = t + u;
    __syncthreads();
  }
  int excl = sm[tid] - myc;
  lstart[tid] = excl;
  lcur[tid] = excl;
  if (tid < nb) gbase[tid] = atomicAdd(&gCur[tid], myc);
  __syncthreads();
  #pragma unroll
  for (int u = 0; u < 4; ++u) {
    if (have[u]) {
      int bin = key[u] >> 24;
      int pos = atomicAdd(&lcur[bin], 1);
      stage[pos] = key[u];
    }
  }
  __syncthreads();
  for (int j = tid; j < cnt; j += 256) {
    unsigned k = stage[j];
    int bin = k >> 24;
    bkt[(size_t)gbase[bin] + (j - lstart[bin])] = k;
  }
}

__global__ __launch_bounds__(256) void k_csr(const unsigned* __restrict__ bkt,
                                             const int* __restrict__ gCur,
                                             int* __restrict__ csr, int* __restrict__ offs,
                                             int n, int nb, int etot) {
  __shared__ int sm[256];
  __shared__ int lstart[256];
  __shared__ int lcur[256];
  __shared__ unsigned itm[CAPB];
  __shared__ ushort_t limg[CAPB];
  int tid = threadIdx.x, b = blockIdx.x;
  int cnt = gCur[b] - b * CAPB;

  int c = 0;
  if (tid < nb) c = gCur[tid] - tid * CAPB;
  sm[tid] = c;
  __syncthreads();
  #pragma unroll
  for (int off = 1; off < 256; off <<= 1) {
    int t = sm[tid];
    int u = (tid >= off) ? sm[tid - off] : 0;
    __syncthreads();
    sm[tid] = t + u;
    __syncthreads();
  }
  int gbase = sm[b] - cnt;
  __syncthreads();

  sm[tid] = 0;
  __syncthreads();
  for (int j = tid; j < cnt; j += 256) {
    unsigned k = bkt[(size_t)b * CAPB + j];
    itm[j] = k;
    atomicAdd(&sm[(k >> 16) & 255], 1);
  }
  __syncthreads();
  int myc = sm[tid];
  #pragma unroll
  for (int off = 1; off < 256; off <<= 1) {
    int t = sm[tid];
    int u = (tid >= off) ? sm[tid - off] : 0;
    __syncthreads();
    sm[tid] = t + u;
    __syncthreads();
  }
  int excl = sm[tid] - myc;
  lstart[tid] = excl;
  lcur[tid] = excl;
  __syncthreads();
  for (int j = tid; j < cnt; j += 256) {
    unsigned k = itm[j];
    int d = (k >> 16) & 255;
    int pos = atomicAdd(&lcur[d], 1);
    limg[pos] = (ushort_t)(k & 0xffffu);
  }
  __syncthreads();
  for (int j = tid; j < cnt; j += 256) csr[gbase + j] = (int)limg[j];
  int gd = b * 256 + tid;
  if (gd < n) offs[gd] = gbase + lstart[tid];
  if (b == nb - 1 && tid == 0) offs[n] = etot;
}

// ---------------- preconvert + gCur init (fused): Wt2/Wt3 bf16-T, layer-1 logit vecs ----------------
// wsd[0..31] = log2e * (W1 @ a_s^T) per head; wsd[32..63] = a_d analog.

__global__ __launch_bounds__(256) void k_wconv(
    const float* __restrict__ W1, const float* __restrict__ as1, const float* __restrict__ ad1,
    const float* __restrict__ W2, const float* __restrict__ W3,
    ushort_t* __restrict__ Wt2, ushort_t* __restrict__ Wt3, float* __restrict__ wsd,
    int* __restrict__ gCur, int nb) {
  int t = blockIdx.x * 256 + threadIdx.x;
  const int np = 128 * 128;
  const int n3 = np + 32 * 128;
  const int nl = n3 + 64;
  if (t < np) {
    int c = t / 128, k = t % 128;
    Wt2[t] = bfbits(W2[k * 128 + c]);
  } else if (t < n3) {
    int i = t - np;
    int c = i / 128, k = i % 128;
    Wt3[i] = bfbits(W3[k * 32 + c]);
  } else if (t < nl) {
    int i = t - n3;
    int h = (i >> 3) & 3, k = i & 7;
    const float* av = (i & 32) ? ad1 : as1;
    float acc = 0.f;
    for (int c = 0; c < 32; ++c) acc += W1[k * 128 + h * 32 + c] * av[h * 32 + c];
    wsd[i] = acc * LOG2E;
  } else if (t < nl + nb) {
    int i = t - nl;
    gCur[i] = i * CAPB;           // bucket cursor init (was k_binit)
  }
}

// ---------------- layer-1 logits: als/ald = x @ (W1 @ a^T), 8-dim dots ----------------

__global__ __launch_bounds__(256) void k_logit1(const float* __restrict__ X,
    const float* __restrict__ wsd, float* __restrict__ als, float* __restrict__ ald, int n) {
  int i = blockIdx.x * 256 + threadIdx.x;
  if (i >= n) return;
  float4 xa = *(const float4*)&X[(size_t)i * 8];
  float4 xb = *(const float4*)&X[(size_t)i * 8 + 4];
  float x[8] = {xa.x, xa.y, xa.z, xa.w, xb.x, xb.y, xb.z, xb.w};
  float sv[4], dv[4];
  #pragma unroll
  for (int h = 0; h < 4; ++h) {
    float s = 0.f, d = 0.f;
    #pragma unroll
    for (int k = 0; k < 8; ++k) {
      s += x[k] * wsd[h * 8 + k];
      d += x[k] * wsd[32 + h * 8 + k];
    }
    sv[h] = s; dv[h] = d;
  }
  *(float4*)&als[(size_t)i * 4] = make_float4(sv[0], sv[1], sv[2], sv[3]);
  *(float4*)&ald[(size_t)i * 4] = make_float4(dv[0], dv[1], dv[2], dv[3]);
}

// ---------------- shared helper ----------------

__device__ __forceinline__ int sel4(int eg, int a, int b, int c, int d) {
  int r = (eg & 1) ? b : a;
  int r2 = (eg & 1) ? d : c;
  return (eg & 2) ? r2 : r;
}

// ---------------- layer-1 aggregate IN X-SPACE (linearity) ----------------

__global__ __launch_bounds__(256) void k_agg4x(const int* __restrict__ offs, const int* __restrict__ csr,
    const float* __restrict__ X, const float* __restrict__ als, const float* __restrict__ ald,
    const float* __restrict__ W1,
    const float* __restrict__ bias, const float* __restrict__ gam, const float* __restrict__ bet,
    const float* __restrict__ mu, const float* __restrict__ var,
    ushort_t* __restrict__ Xo, int n) {
  constexpr int UB = 6;
  constexpr int CAPW = 252;
  __shared__ int   s_idx[4][CAPW];
  __shared__ float s_exp[4][CAPW * 4];
  __shared__ float aggL[4][4][4][8];   // [wslot][node][head][dim]
  int wslot = threadIdx.x >> 6;
  int wid = (blockIdx.x * 256 + threadIdx.x) >> 6;
  int v0 = wid * 4;
  if (v0 >= n) return;                 // per-wave LDS; no barriers
  int lane = threadIdx.x & 63;

  int va = v0, vb = min(v0 + 1, n), vc = min(v0 + 2, n), vd = min(v0 + 3, n);
  int o0 = offs[va], o1 = offs[vb], o2 = offs[vc], o3 = offs[vd], o4 = offs[min(v0 + 4, n)];
  int d0 = o1 - o0, d1 = o2 - o1, d2 = o3 - o2, d3 = o4 - o3;

  int room = CAPW;
  int ms0 = min(d0, room); int mp0 = min((ms0 + UB - 1) / UB * UB, room); ms0 = min(ms0, mp0); room -= mp0;
  int ms1 = min(d1, room); int mp1 = min((ms1 + UB - 1) / UB * UB, room); ms1 = min(ms1, mp1); room -= mp1;
  int ms2 = min(d2, room); int mp2 = min((ms2 + UB - 1) / UB * UB, room); ms2 = min(ms2, mp2); room -= mp2;
  int ms3 = min(d3, room); int mp3 = min((ms3 + UB - 1) / UB * UB, room); ms3 = min(ms3, mp3);
  int p0 = 0, p1 = mp0, p2 = mp0 + mp1, p3 = mp0 + mp1 + mp2;

  int total = o4 - o0;
  for (int l = lane; l < total; l += 64) {
    int j = o0 + l;
    int nd = (j >= o1) + (j >= o2) + (j >= o3);
    int cbase = sel4(nd, o0 - p0, o1 - p1, o2 - p2, o3 - p3);
    int lim   = sel4(nd, p0 + ms0, p1 + ms1, p2 + ms2, p3 + ms3);
    int pos = j - cbase;
    if (pos < lim) {
      int s = csr[j];
      s_idx[wslot][pos] = s << 5;       // 8 floats = 32B per x row
      const float4 av = *(const float4*)&als[(size_t)s * 4];
      const float4 dv = *(const float4*)&ald[(size_t)(v0 + nd) * 4];
      float e0 = av.x + dv.x, e1 = av.y + dv.y, e2 = av.z + dv.z, e3 = av.w + dv.w;
      e0 = fmaxf(e0, 0.2f * e0); e1 = fmaxf(e1, 0.2f * e1);
      e2 = fmaxf(e2, 0.2f * e2); e3 = fmaxf(e3, 0.2f * e3);
      *(float4*)&s_exp[wslot][pos * 4] = make_float4(fexp2(e0), fexp2(e1), fexp2(e2), fexp2(e3));
    }
  }
  if (lane < 4 * UB) {
    int v = lane / UB, q = lane % UB;
    int msv = sel4(v, ms0, ms1, ms2, ms3);
    int mpv = sel4(v, mp0, mp1, mp2, mp3);
    int pv  = sel4(v, p0, p1, p2, p3);
    if (q < mpv - msv) {
      int pos = pv + msv + q;
      s_idx[wslot][pos] = 0;
      *(float4*)&s_exp[wslot][pos * 4] = make_float4(0.f, 0.f, 0.f, 0.f);
    }
  }

  int eg = lane >> 4;
  int fl = lane & 15;
  int myh = fl >> 2;
  int kp = fl & 3;
  int st  = sel4(eg, p0, p1, p2, p3);
  int mpv = sel4(eg, mp0, mp1, mp2, mp3);
  int msv = sel4(eg, ms0, ms1, ms2, ms3);
  int dgv = sel4(eg, d0, d1, d2, d3);
  int obv = sel4(eg, o0, o1, o2, o3);
  const char* xb = (const char*)X + kp * 8;

  f32x2 accx = (f32x2){0.f, 0.f};
  float den = 0.f;

  for (int j0 = 0; j0 < mpv; j0 += UB) {
    int ss[UB]; float ex[UB];
    #pragma unroll
    for (int u = 0; u < UB; ++u) {
      int pidx = st + j0 + u;
      ss[u] = s_idx[wslot][pidx];
      ex[u] = s_exp[wslot][pidx * 4 + myh];
    }
    f32x2 xv[UB];
    #pragma unroll
    for (int u = 0; u < UB; ++u)
      xv[u] = *(const f32x2*)(xb + (size_t)(unsigned)ss[u]);
    #pragma unroll
    for (int u = 0; u < UB; ++u)
      pkfma(accx, (f32x2){ex[u], ex[u]}, xv[u]);
    den += ((ex[0] + ex[1]) + (ex[2] + ex[3])) + (ex[4] + ex[5]);
  }
  if (dgv > msv) {
    float myald = ald[(size_t)(v0 + eg) * 4 + myh];
    for (int j = msv; j < dgv; ++j) {
      int s = csr[obv + j];
      float e = als[(size_t)s * 4 + myh] + myald;
      e = fmaxf(e, 0.2f * e);
      float exv = fexp2(e);
      den += exv;
      f32x2 xv = *(const f32x2*)(xb + ((size_t)s << 5));
      pkfma(accx, (f32x2){exv, exv}, xv);
    }
  }

  aggL[wslot][eg][myh][kp * 2]     = accx.x;
  aggL[wslot][eg][myh][kp * 2 + 1] = accx.y;

  int node = v0 + eg;
  if (node >= n) return;
  float inv = 1.f / (den + 1e-16f);
  float ax[8];
  *(float4*)&ax[0] = *(const float4*)&aggL[wslot][eg][myh][0];
  *(float4*)&ax[4] = *(const float4*)&aggL[wslot][eg][myh][4];

  int f0 = fl * 8;
  float acc[8];
  #pragma unroll
  for (int q = 0; q < 8; ++q) acc[q] = 0.f;
  #pragma unroll
  for (int k = 0; k < 8; ++k) {
    float4 w0 = *(const float4*)&W1[k * 128 + f0];
    float4 w1 = *(const float4*)&W1[k * 128 + f0 + 4];
    acc[0] += ax[k] * w0.x; acc[1] += ax[k] * w0.y;
    acc[2] += ax[k] * w0.z; acc[3] += ax[k] * w0.w;
    acc[4] += ax[k] * w1.x; acc[5] += ax[k] * w1.y;
    acc[6] += ax[k] * w1.z; acc[7] += ax[k] * w1.w;
  }

  float4 bi0 = *(const float4*)&bias[f0], bi1 = *(const float4*)&bias[f0 + 4];
  float4 mu0 = *(const float4*)&mu[f0],   mu1 = *(const float4*)&mu[f0 + 4];
  float4 va0 = *(const float4*)&var[f0],  va1 = *(const float4*)&var[f0 + 4];
  float4 ga0 = *(const float4*)&gam[f0],  ga1 = *(const float4*)&gam[f0 + 4];
  float4 be0 = *(const float4*)&bet[f0],  be1 = *(const float4*)&bet[f0 + 4];
  float bb[8] = {bi0.x, bi0.y, bi0.z, bi0.w, bi1.x, bi1.y, bi1.z, bi1.w};
  float mm[8] = {mu0.x, mu0.y, mu0.z, mu0.w, mu1.x, mu1.y, mu1.z, mu1.w};
  float vv[8] = {va0.x, va0.y, va0.z, va0.w, va1.x, va1.y, va1.z, va1.w};
  float gg[8] = {ga0.x, ga0.y, ga0.z, ga0.w, ga1.x, ga1.y, ga1.z, ga1.w};
  float ee[8] = {be0.x, be0.y, be0.z, be0.w, be1.x, be1.y, be1.z, be1.w};
  float ov[8];
  #pragma unroll
  for (int q = 0; q < 8; ++q) {
    float xo = acc[q] * inv + bb[q];
    xo = (xo - mm[q]) * rsqrtf(vv[q] + BN_EPS) * gg[q] + ee[q];
    ov[q] = (xo > 0.f) ? xo : (__expf(xo) - 1.f);
  }
  uint4 pk;
  pk.x = packbf2(ov[0], ov[1]); pk.y = packbf2(ov[2], ov[3]);
  pk.z = packbf2(ov[4], ov[5]); pk.w = packbf2(ov[6], ov[7]);
  *(uint4*)&Xo[(size_t)node * 128 + f0] = pk;
}

// ---------------- MFMA GEMM (K=128): H(bf16) = X(bf16) @ W(bf16), + logit dots ----------------

template<int FOUT>
__global__ __launch_bounds__(256) void k_gemm_mfma(
    const ushort_t* __restrict__ X, const ushort_t* __restrict__ Wt,
    const float* __restrict__ a_s, const float* __restrict__ a_d,
    ushort_t* __restrict__ Hout, float* __restrict__ als, float* __restrict__ ald, int n) {
  constexpr int HEADS = FOUT / 32;
  constexpr int BM = (FOUT == 128) ? 64 : 256;
  constexpr int LDC = FOUT + 8;
  __shared__ ushort_t Ct[BM * LDC];
  int tid = threadIdx.x;
  int w = tid >> 6, lane = tid & 63;
  int lo = lane & 15, hi = lane >> 4;
  int rowB = blockIdx.x * BM;
  int row0 = (FOUT == 128) ? rowB : rowB + w * 64;
  int nbase = (FOUT == 128) ? w * 32 : 0;
  int h = (FOUT == 128) ? w : 0;

  f32x4v acc[4][2];
  #pragma unroll
  for (int mf = 0; mf < 4; ++mf)
    #pragma unroll
    for (int nf = 0; nf < 2; ++nf) acc[mf][nf] = (f32x4v){0.f, 0.f, 0.f, 0.f};

  #pragma unroll
  for (int k0 = 0; k0 < 4; ++k0) {
    int kof = k0 * 32 + hi * 8;
    short8 b[2];
    #pragma unroll
    for (int nf = 0; nf < 2; ++nf) {
      int col = nbase + nf * 16 + lo;
      b[nf] = *(const short8*)&Wt[(size_t)col * 128 + kof];
    }
    short8 a[4];
    #pragma unroll
    for (int mf = 0; mf < 4; ++mf) {
      int row = row0 + mf * 16 + lo;
      row = min(row, n - 1);
      a[mf] = *(const short8*)&X[(size_t)row * 128 + kof];
    }
    #pragma unroll
    for (int mf = 0; mf < 4; ++mf)
      #pragma unroll
      for (int nf = 0; nf < 2; ++nf)
        acc[mf][nf] = __builtin_amdgcn_mfma_f32_16x16x32_bf16(a[mf], b[nf], acc[mf][nf], 0, 0, 0);
  }

  float as0 = a_s[h * 32 + lo] * LOG2E, as1 = a_s[h * 32 + 16 + lo] * LOG2E;
  float ad0 = a_d[h * 32 + lo] * LOG2E, ad1 = a_d[h * 32 + 16 + lo] * LOG2E;
  #pragma unroll
  for (int mf = 0; mf < 4; ++mf) {
    #pragma unroll
    for (int j = 0; j < 4; ++j) {
      float ps = acc[mf][0][j] * as0 + acc[mf][1][j] * as1;
      float pd = acc[mf][0][j] * ad0 + acc[mf][1][j] * ad1;
      #pragma unroll
      for (int m = 1; m < 16; m <<= 1) {
        ps += __shfl_xor(ps, m, 64);
        pd += __shfl_xor(pd, m, 64);
      }
      if (lo == 0) {
        int row = row0 + mf * 16 + hi * 4 + j;
        if (row < n) {
          als[(size_t)row * HEADS + h] = ps;
          ald[(size_t)row * HEADS + h] = pd;
        }
      }
    }
  }

  #pragma unroll
  for (int mf = 0; mf < 4; ++mf) {
    int rL = ((FOUT == 128) ? 0 : w * 64) + mf * 16 + hi * 4;
    #pragma unroll
    for (int nf = 0; nf < 2; ++nf) {
      int cL = nbase + nf * 16 + lo;
      #pragma unroll
      for (int j = 0; j < 4; ++j)
        Ct[(rL + j) * LDC + cL] = bfbits(acc[mf][nf][j]);
    }
  }
  __syncthreads();
  constexpr int CPR = FOUT / 8;
  #pragma unroll
  for (int i = 0; i < (BM * CPR) / 256; ++i) {
    int idx = tid + i * 256;
    int r = idx / CPR, c = idx % CPR;
    int grow = rowB + r;
    if (grow < n)
      *(uint4*)&Hout[(size_t)grow * FOUT + c * 8] = *(const uint4*)&Ct[r * LDC + c * 8];
  }
}

// ---------------- agg for HEADS=4/FEAT=128 (layer 2): 4 nodes/wave, 16 lanes/node ----------------

__global__ __launch_bounds__(256) void k_agg4(const int* __restrict__ offs, const int* __restrict__ csr,
    const ushort_t* __restrict__ Hb, const float* __restrict__ als, const float* __restrict__ ald,
    const float* __restrict__ bias, const float* __restrict__ gam, const float* __restrict__ bet,
    const float* __restrict__ mu, const float* __restrict__ var,
    ushort_t* __restrict__ Xo, int n) {
  constexpr int UB = 6;
  constexpr int CAPW = 252;
  __shared__ int   s_idx[4][CAPW];
  __shared__ float s_exp[4][CAPW * 4];
  int wslot = threadIdx.x >> 6;
  int wid = (blockIdx.x * 256 + threadIdx.x) >> 6;
  int v0 = wid * 4;
  if (v0 >= n) return;
  int lane = threadIdx.x & 63;

  int va = v0, vb = min(v0 + 1, n), vc = min(v0 + 2, n), vd = min(v0 + 3, n);
  int o0 = offs[va], o1 = offs[vb], o2 = offs[vc], o3 = offs[vd], o4 = offs[min(v0 + 4, n)];
  int d0 = o1 - o0, d1 = o2 - o1, d2 = o3 - o2, d3 = o4 - o3;

  int room = CAPW;
  int ms0 = min(d0, room); int mp0 = min((ms0 + UB - 1) / UB * UB, room); ms0 = min(ms0, mp0); room -= mp0;
  int ms1 = min(d1, room); int mp1 = min((ms1 + UB - 1) / UB * UB, room); ms1 = min(ms1, mp1); room -= mp1;
  int ms2 = min(d2, room); int mp2 = min((ms2 + UB - 1) / UB * UB, room); ms2 = min(ms2, mp2); room -= mp2;
  int ms3 = min(d3, room); int mp3 = min((ms3 + UB - 1) / UB * UB, room); ms3 = min(ms3, mp3);
  int p0 = 0, p1 = mp0, p2 = mp0 + mp1, p3 = mp0 + mp1 + mp2;

  int total = o4 - o0;
  for (int l = lane; l < total; l += 64) {
    int j = o0 + l;
    int nd = (j >= o1) + (j >= o2) + (j >= o3);
    int cbase = sel4(nd, o0 - p0, o1 - p1, o2 - p2, o3 - p3);
    int lim   = sel4(nd, p0 + ms0, p1 + ms1, p2 + ms2, p3 + ms3);
    int pos = j - cbase;
    if (pos < lim) {
      int s = csr[j];
      s_idx[wslot][pos] = s << 8;
      const float4 av = *(const float4*)&als[(size_t)s * 4];
      const float4 dv = *(const float4*)&ald[(size_t)(v0 + nd) * 4];
      float e0 = av.x + dv.x, e1 = av.y + dv.y, e2 = av.z + dv.z, e3 = av.w + dv.w;
      e0 = fmaxf(e0, 0.2f * e0); e1 = fmaxf(e1, 0.2f * e1);
      e2 = fmaxf(e2, 0.2f * e2); e3 = fmaxf(e3, 0.2f * e3);
      *(float4*)&s_exp[wslot][pos * 4] = make_float4(fexp2(e0), fexp2(e1), fexp2(e2), fexp2(e3));
    }
  }
  if (lane < 4 * UB) {
    int v = lane / UB, q = lane % UB;
    int msv = sel4(v, ms0, ms1, ms2, ms3);
    int mpv = sel4(v, mp0, mp1, mp2, mp3);
    int pv  = sel4(v, p0, p1, p2, p3);
    if (q < mpv - msv) {
      int pos = pv + msv + q;
      s_idx[wslot][pos] = 0;
      *(float4*)&s_exp[wslot][pos * 4] = make_float4(0.f, 0.f, 0.f, 0.f);
    }
  }

  int eg = lane >> 4;
  int fl = lane & 15;
  int f0 = fl * 8;
  int myh = f0 >> 5;
  int st  = sel4(eg, p0, p1, p2, p3);
  int mpv = sel4(eg, mp0, mp1, mp2, mp3);
  int msv = sel4(eg, ms0, ms1, ms2, ms3);
  int dgv = sel4(eg, d0, d1, d2, d3);
  int obv = sel4(eg, o0, o1, o2, o3);
  const char* hb = (const char*)Hb + f0 * 2;

  f32x2 acc2[4];
  #pragma unroll
  for (int q = 0; q < 4; ++q) acc2[q] = (f32x2){0.f, 0.f};
  float den = 0.f;

  for (int j0 = 0; j0 < mpv; j0 += UB) {
    int ss[UB]; float ex[UB];
    #pragma unroll
    for (int u = 0; u < UB; ++u) {
      int pidx = st + j0 + u;
      ss[u] = s_idx[wslot][pidx];
      ex[u] = s_exp[wslot][pidx * 4 + myh];
    }
    uint4 pv[UB];
    #pragma unroll
    for (int u = 0; u < UB; ++u)
      pv[u] = *(const uint4*)(hb + (size_t)(unsigned)ss[u]);
    #pragma unroll
    for (int u = 0; u < UB; ++u) {
      f32x2 e2v = (f32x2){ex[u], ex[u]};
      pkfma(acc2[0], e2v, (f32x2){blo(pv[u].x), bhi(pv[u].x)});
      pkfma(acc2[1], e2v, (f32x2){blo(pv[u].y), bhi(pv[u].y)});
      pkfma(acc2[2], e2v, (f32x2){blo(pv[u].z), bhi(pv[u].z)});
      pkfma(acc2[3], e2v, (f32x2){blo(pv[u].w), bhi(pv[u].w)});
    }
    den += ((ex[0] + ex[1]) + (ex[2] + ex[3])) + (ex[4] + ex[5]);
  }
  if (dgv > msv) {
    float myald = ald[(size_t)(v0 + eg) * 4 + myh];
    for (int j = msv; j < dgv; ++j) {
      int s = csr[obv + j];
      float e = als[(size_t)s * 4 + myh] + myald;
      e = fmaxf(e, 0.2f * e);
      float exv = fexp2(e);
      den += exv;
      uint4 pv = *(const uint4*)(Hb + (size_t)s * 128 + f0);
      f32x2 e2v = (f32x2){exv, exv};
      pkfma(acc2[0], e2v, (f32x2){blo(pv.x), bhi(pv.x)});
      pkfma(acc2[1], e2v, (f32x2){blo(pv.y), bhi(pv.y)});
      pkfma(acc2[2], e2v, (f32x2){blo(pv.z), bhi(pv.z)});
      pkfma(acc2[3], e2v, (f32x2){blo(pv.w), bhi(pv.w)});
    }
  }

  int node = v0 + eg;
  if (node >= n) return;
  float acc[8] = {acc2[0].x, acc2[0].y, acc2[1].x, acc2[1].y,
                  acc2[2].x, acc2[2].y, acc2[3].x, acc2[3].y};
  float inv = 1.f / (den + 1e-16f);
  float4 bi0 = *(const float4*)&bias[f0], bi1 = *(const float4*)&bias[f0 + 4];
  float4 mu0 = *(const float4*)&mu[f0],   mu1 = *(const float4*)&mu[f0 + 4];
  float4 va0 = *(const float4*)&var[f0],  va1 = *(const float4*)&var[f0 + 4];
  float4 ga0 = *(const float4*)&gam[f0],  ga1 = *(const float4*)&gam[f0 + 4];
  float4 be0 = *(const float4*)&bet[f0],  be1 = *(const float4*)&bet[f0 + 4];
  float bb[8] = {bi0.x, bi0.y, bi0.z, bi0.w, bi1.x, bi1.y, bi1.z, bi1.w};
  float mm[8] = {mu0.x, mu0.y, mu0.z, mu0.w, mu1.x, mu1.y, mu1.z, mu1.w};
  float vv[8] = {va0.x, va0.y, va0.z, va0.w, va1.x, va1.y, va1.z, va1.w};
  float gg[8] = {ga0.x, ga0.y, ga0.z, ga0.w, ga1.x, ga1.y, ga1.z, ga1.w};
  float ee[8] = {be0.x, be0.y, be0.z, be0.w, be1.x, be1.y, be1.z, be1.w};
  float ov[8];
  #pragma unroll
  for (int q = 0; q < 8; ++q) {
    float xo = acc[q] * inv + bb[q];
    xo = (xo - mm[q]) * rsqrtf(vv[q] + BN_EPS) * gg[q] + ee[q];
    ov[q] = (xo > 0.f) ? xo : (__expf(xo) - 1.f);
  }
  uint4 pk;
  pk.x = packbf2(ov[0], ov[1]); pk.y = packbf2(ov[2], ov[3]);
  pk.z = packbf2(ov[4], ov[5]); pk.w = packbf2(ov[6], ov[7]);
  *(uint4*)&Xo[(size_t)node * 128 + f0] = pk;
}

// ---------------- layer-3 agg + BN + ELU + FUSED classifier -> sigmoid out ----------------
// After the butterfly reduce every lane holds the complete 8-feature slice for
// its fl = lane%4 group; lanes {l, l^1, l^2, l^3} jointly hold all 32 features.
// Classifier: per-lane 16 hidden partials (8 feats each), 2-step xor all-reduce,
// ReLU + dot(cW2), sigmoid; lane 0 stores out[node].

__global__ __launch_bounds__(256) void k_agg1c(const int* __restrict__ offs, const int* __restrict__ csr,
    const ushort_t* __restrict__ Hb, const float* __restrict__ als, const float* __restrict__ ald,
    const float* __restrict__ bias, const float* __restrict__ gam, const float* __restrict__ bet,
    const float* __restrict__ mu, const float* __restrict__ var,
    const float* __restrict__ cW1, const float* __restrict__ cb1,
    const float* __restrict__ cW2, const float* __restrict__ cb2,
    float* __restrict__ out, int n) {
  constexpr int LPF = 4;
  constexpr int EPW = 16;
  constexpr int UB = 2;
  constexpr int STEP = 32;
  constexpr int CAP = 128;
  __shared__ int   s_idx[4][CAP];
  __shared__ float s_exp[4][CAP];
  int wslot = threadIdx.x >> 6;
  int wv = (blockIdx.x * 256 + threadIdx.x) >> 6;
  if (wv >= n) return;
  int lane = threadIdx.x & 63;
  int rs = offs[wv];
  int deg = offs[wv + 1] - rs;
  int dstage = deg < CAP ? deg : CAP;
  int dpad = ((dstage + STEP - 1) / STEP) * STEP;
  float ald0 = ald[wv];

  for (int j = lane; j < dpad; j += 64) {
    if (j < dstage) {
      int s = csr[rs + j];
      s_idx[wslot][j] = s << 6;
      float e = als[s] + ald0;
      e = fmaxf(e, 0.2f * e);
      s_exp[wslot][j] = fexp2(e);
    } else {
      s_idx[wslot][j] = 0;
      s_exp[wslot][j] = 0.f;
    }
  }

  int fl = lane % LPF;
  int eg = lane / LPF;
  int f0 = fl * 8;
  const char* hb = (const char*)Hb + f0 * 2;

  f32x2 acc2[4];
  #pragma unroll
  for (int q = 0; q < 4; ++q) acc2[q] = (f32x2){0.f, 0.f};
  float den = 0.f;

  for (int j0 = eg; j0 < dpad; j0 += STEP) {
    int ss[UB]; float ex[UB];
    #pragma unroll
    for (int u = 0; u < UB; ++u) {
      int j = j0 + u * EPW;
      ss[u] = s_idx[wslot][j];
      ex[u] = s_exp[wslot][j];
    }
    uint4 pv[UB];
    #pragma unroll
    for (int u = 0; u < UB; ++u)
      pv[u] = *(const uint4*)(hb + (size_t)(unsigned)ss[u]);
    #pragma unroll
    for (int u = 0; u < UB; ++u) {
      f32x2 e2v = (f32x2){ex[u], ex[u]};
      pkfma(acc2[0], e2v, (f32x2){blo(pv[u].x), bhi(pv[u].x)});
      pkfma(acc2[1], e2v, (f32x2){blo(pv[u].y), bhi(pv[u].y)});
      pkfma(acc2[2], e2v, (f32x2){blo(pv[u].z), bhi(pv[u].z)});
      pkfma(acc2[3], e2v, (f32x2){blo(pv[u].w), bhi(pv[u].w)});
      den += ex[u];
    }
  }
  if (deg > CAP) {
    for (int j = CAP + eg; j < deg; j += EPW) {
      int s = csr[rs + j];
      float e = als[s] + ald0;
      e = fmaxf(e, 0.2f * e);
      float exv = fexp2(e);
      den += exv;
      uint4 pv = *(const uint4*)(Hb + (size_t)s * 32 + f0);
      f32x2 e2v = (f32x2){exv, exv};
      pkfma(acc2[0], e2v, (f32x2){blo(pv.x), bhi(pv.x)});
      pkfma(acc2[1], e2v, (f32x2){blo(pv.y), bhi(pv.y)});
      pkfma(acc2[2], e2v, (f32x2){blo(pv.z), bhi(pv.z)});
      pkfma(acc2[3], e2v, (f32x2){blo(pv.w), bhi(pv.w)});
    }
  }

  float acc[8] = {acc2[0].x, acc2[0].y, acc2[1].x, acc2[1].y,
                  acc2[2].x, acc2[2].y, acc2[3].x, acc2[3].y};
  #pragma unroll
  for (int off = 32; off >= LPF; off >>= 1) {
    den += __shfl_xor(den, off, 64);
    #pragma unroll
    for (int q = 0; q < 8; ++q) acc[q] += __shfl_xor(acc[q], off, 64);
  }
  float inv = 1.f / (den + 1e-16f);

  // BN + ELU on all lanes (x3 features f0..f0+7, complete per lane)
  float ov[8];
  #pragma unroll
  for (int q = 0; q < 8; ++q) {
    int f = f0 + q;
    float xo = acc[q] * inv + bias[f];
    xo = (xo - mu[f]) * rsqrtf(var[f] + BN_EPS) * gam[f] + bet[f];
    ov[q] = (xo > 0.f) ? xo : (__expf(xo) - 1.f);
  }

  // fused classifier: hidden partials over this lane's 8 features
  float hp[16];
  #pragma unroll
  for (int j = 0; j < 16; ++j) {
    float s = 0.f;
    #pragma unroll
    for (int k = 0; k < 8; ++k) s += ov[k] * cW1[(f0 + k) * 16 + j];
    hp[j] = s;
  }
  #pragma unroll
  for (int j = 0; j < 16; ++j) {
    hp[j] += __shfl_xor(hp[j], 1, 64);
    hp[j] += __shfl_xor(hp[j], 2, 64);
  }
  if (lane == 0) {
    float o = cb2[0];
    #pragma unroll
    for (int j = 0; j < 16; ++j) {
      float hs = fmaxf(hp[j] + cb1[j], 0.f);
      o += hs * cW2[j];
    }
    out[wv] = 1.f / (1.f + __expf(-o));
  }
}

// ---------------- host ----------------

static inline size_t align256(size_t x) { return (x + 255) & ~(size_t)255; }

extern "C" void kernel_launch(void* const* d_in, const int* in_sizes, int n_in,
                              void* d_out, int out_size, void* d_ws, size_t ws_size,
                              hipStream_t stream) {
  const float* x   = (const float*)d_in[0];
  const int*   ei  = (const int*)d_in[1];
  const float* W1  = (const float*)d_in[2];
  const float* as1 = (const float*)d_in[3];
  const float* ad1 = (const float*)d_in[4];
  const float* b1  = (const float*)d_in[5];
  const float* g1  = (const float*)d_in[6];
  const float* be1 = (const float*)d_in[7];
  const float* m1  = (const float*)d_in[8];
  const float* v1  = (const float*)d_in[9];
  const float* W2  = (const float*)d_in[10];
  const float* as2 = (const float*)d_in[11];
  const float* ad2 = (const float*)d_in[12];
  const float* b2  = (const float*)d_in[13];
  const float* g2  = (const float*)d_in[14];
  const float* be2 = (const float*)d_in[15];
  const float* m2  = (const float*)d_in[16];
  const float* v2  = (const float*)d_in[17];
  const float* W3  = (const float*)d_in[18];
  const float* as3 = (const float*)d_in[19];
  const float* ad3 = (const float*)d_in[20];
  const float* b3  = (const float*)d_in[21];
  const float* g3  = (const float*)d_in[22];
  const float* be3 = (const float*)d_in[23];
  const float* m3  = (const float*)d_in[24];
  const float* v3  = (const float*)d_in[25];
  const float* cW1 = (const float*)d_in[26];
  const float* cb1 = (const float*)d_in[27];
  const float* cW2 = (const float*)d_in[28];
  const float* cb2 = (const float*)d_in[29];

  const int n = in_sizes[0] / 8;
  const int E = in_sizes[1] / 2;
  const int etot = E + n;
  const int nb = (n + 255) / 256;

  // workspace carve
  char* p = (char*)d_ws;
  int* offs   = (int*)p;  p += align256((size_t)(n + 1) * 4);
  int* csr    = (int*)p;  p += align256((size_t)etot * 4);
  int* gCur   = (int*)p;  p += align256(1024);
  unsigned* bkt = (unsigned*)p; p += align256((size_t)nb * CAPB * 4);
  float* als  = (float*)p; p += align256((size_t)n * 4 * 4);
  float* ald  = (float*)p; p += align256((size_t)n * 4 * 4);
  ushort_t* bufH = (ushort_t*)p; p += align256((size_t)n * 128 * 2);  // bf16 H (layers 2,3)
  ushort_t* bufX = (ushort_t*)p; p += align256((size_t)n * 128 * 2);  // bf16 layer output
  ushort_t* wt2 = (ushort_t*)p; p += align256(128 * 128 * 2);
  ushort_t* wt3 = (ushort_t*)p; p += align256(32 * 128 * 2);
  float* wsd  = (float*)p; p += align256(64 * 4);                      // layer-1 logit vecs

  // preconvert + gCur init, then CSR build
  k_wconv<<<82, 256, 0, stream>>>(W1, as1, ad1, W2, W3, wt2, wt3, wsd, gCur, nb);
  k_bucket<<<(etot + 1023) / 1024, 256, 0, stream>>>(ei, E, etot, bkt, gCur, nb);
  k_csr<<<nb, 256, 0, stream>>>(bkt, gCur, csr, offs, n, nb, etot);

  const int ga4 = (n + 15) / 16;   // 16 nodes/block (4 waves x 4 nodes)
  const int ga1 = (n + 3) / 4;     // 4 nodes/block

  // layer 1: logits + x-space aggregate (W1 applied post-aggregation; linearity)
  k_logit1<<<(n + 255) / 256, 256, 0, stream>>>(x, wsd, als, ald, n);
  k_agg4x<<<ga4, 256, 0, stream>>>(offs, csr, x, als, ald, W1, b1, g1, be1, m1, v1, bufX, n);

  // layer 2: MFMA GEMM + agg
  k_gemm_mfma<128><<<(n + 63) / 64, 256, 0, stream>>>(bufX, wt2, as2, ad2, bufH, als, ald, n);
  k_agg4<<<ga4, 256, 0, stream>>>(offs, csr, bufH, als, ald, b2, g2, be2, m2, v2, bufX, n);

  // layer 3: MFMA GEMM + agg with fused BN/ELU/classifier -> d_out
  k_gemm_mfma<32><<<(n + 255) / 256, 256, 0, stream>>>(bufX, wt3, as3, ad3, bufH, als, ald, n);
  k_agg1c<<<ga1, 256, 0, stream>>>(offs, csr, bufH, als, ald, b3, g3, be3, m3, v3,
                                   cW1, cb1, cW2, cb2, (float*)d_out, n);
}

// Round 16
// 167.138 us; speedup vs baseline: 1.9388x; 1.9388x over previous
//
#include <hip/hip_runtime.h>
#include <hip/hip_bf16.h>

#define BN_EPS 1e-5f
#define CAPB 6144   // bucket slack capacity; mean load 4337, +27 sigma
#define LOG2E 1.4426950408889634f

typedef unsigned short ushort_t;
typedef __attribute__((ext_vector_type(2))) float f32x2;
typedef __attribute__((ext_vector_type(4))) float f32x4v;
typedef __attribute__((ext_vector_type(8))) short short8;

__device__ __forceinline__ float blo(unsigned w) { unsigned t = w << 16; return __builtin_bit_cast(float, t); }
__device__ __forceinline__ float bhi(unsigned w) { unsigned t = w & 0xffff0000u; return __builtin_bit_cast(float, t); }
__device__ __forceinline__ ushort_t bfbits(float a) {
  return (ushort_t)__builtin_bit_cast(unsigned short, __float2bfloat16(a));
}
__device__ __forceinline__ unsigned packbf2(float a, float b) {
  unsigned lo = (unsigned)bfbits(a);
  unsigned hi = (unsigned)bfbits(b);
  return lo | (hi << 16);
}
__device__ __forceinline__ float fexp2(float x) {
#if __has_builtin(__builtin_amdgcn_exp2f)
  return __builtin_amdgcn_exp2f(x);
#else
  return exp2f(x);
#endif
}
__device__ __forceinline__ void pkfma(f32x2& d, f32x2 a, f32x2 b) {
  asm("v_pk_fma_f32 %0, %1, %2, %0" : "+v"(d) : "v"(a), "v"(b));
}

// ---------------- CSR build: bucketed two-pass, coalesced ----------------
// key = (dst<<16)|src  (both < 65536). bin = dst>>8.

__global__ __launch_bounds__(256) void k_bucket(const int* __restrict__ ei, int E, int etot,
                                                unsigned* __restrict__ bkt, int* __restrict__ gCur,
                                                int nb) {
  __shared__ int sm[256];
  __shared__ int lstart[256];
  __shared__ int lcur[256];
  __shared__ int gbase[256];
  __shared__ unsigned stage[1024];
  int tid = threadIdx.x;
  int base = blockIdx.x * 1024;
  int cnt = etot - base; if (cnt > 1024) cnt = 1024;

  sm[tid] = 0;
  __syncthreads();
  unsigned key[4]; int have[4];
  #pragma unroll
  for (int u = 0; u < 4; ++u) {
    int idx = tid + u * 256;
    have[u] = (idx < cnt);
    if (have[u]) {
      int i = base + idx;
      int s, d;
      if (i < E) { s = ei[i]; d = ei[E + i]; }
      else       { s = i - E; d = s; }
      unsigned k = ((unsigned)d << 16) | (unsigned)s;
      key[u] = k;
      atomicAdd(&sm[k >> 24], 1);
    }
  }
  __syncthreads();
  int myc = sm[tid];
  #pragma unroll
  for (int off = 1; off < 256; off <<= 1) {
    int t = sm[tid];
    int u = (tid >= off) ? sm[tid - off] : 0;
    __syncthreads();
    sm[tid] = t + u;
    __syncthreads();
  }
  int excl = sm[tid] - myc;
  lstart[tid] = excl;
  lcur[tid] = excl;
  if (tid < nb) gbase[tid] = atomicAdd(&gCur[tid], myc);
  __syncthreads();
  #pragma unroll
  for (int u = 0; u < 4; ++u) {
    if (have[u]) {
      int bin = key[u] >> 24;
      int pos = atomicAdd(&lcur[bin], 1);
      stage[pos] = key[u];
    }
  }
  __syncthreads();
  for (int j = tid; j < cnt; j += 256) {
    unsigned k = stage[j];
    int bin = k >> 24;
    bkt[(size_t)gbase[bin] + (j - lstart[bin])] = k;
  }
}

__global__ __launch_bounds__(256) void k_csr(const unsigned* __restrict__ bkt,
                                             const int* __restrict__ gCur,
                                             int* __restrict__ csr, int* __restrict__ offs,
                                             int n, int nb, int etot) {
  __shared__ int sm[256];
  __shared__ int lstart[256];
  __shared__ int lcur[256];
  __shared__ unsigned itm[CAPB];
  __shared__ ushort_t limg[CAPB];
  int tid = threadIdx.x, b = blockIdx.x;
  int cnt = gCur[b] - b * CAPB;

  int c = 0;
  if (tid < nb) c = gCur[tid] - tid * CAPB;
  sm[tid] = c;
  __syncthreads();
  #pragma unroll
  for (int off = 1; off < 256; off <<= 1) {
    int t = sm[tid];
    int u = (tid >= off) ? sm[tid - off] : 0;
    __syncthreads();
    sm[tid] = t + u;
    __syncthreads();
  }
  int gbase = sm[b] - cnt;
  __syncthreads();

  sm[tid] = 0;
  __syncthreads();
  for (int j = tid; j < cnt; j += 256) {
    unsigned k = bkt[(size_t)b * CAPB + j];
    itm[j] = k;
    atomicAdd(&sm[(k >> 16) & 255], 1);
  }
  __syncthreads();
  int myc = sm[tid];
  #pragma unroll
  for (int off = 1; off < 256; off <<= 1) {
    int t = sm[tid];
    int u = (tid >= off) ? sm[tid - off] : 0;
    __syncthreads();
    sm[tid] = t + u;
    __syncthreads();
  }
  int excl = sm[tid] - myc;
  lstart[tid] = excl;
  lcur[tid] = excl;
  __syncthreads();
  for (int j = tid; j < cnt; j += 256) {
    unsigned k = itm[j];
    int d = (k >> 16) & 255;
    int pos = atomicAdd(&lcur[d], 1);
    limg[pos] = (ushort_t)(k & 0xffffu);
  }
  __syncthreads();
  for (int j = tid; j < cnt; j += 256) csr[gbase + j] = (int)limg[j];
  int gd = b * 256 + tid;
  if (gd < n) offs[gd] = gbase + lstart[tid];
  if (b == nb - 1 && tid == 0) offs[n] = etot;
}

// ---------------- preconvert + gCur init (fused): Wt2/Wt3 bf16-T, layer-1 logit vecs ----------------
// wsd[0..31] = log2e * (W1 @ a_s^T) per head; wsd[32..63] = a_d analog.

__global__ __launch_bounds__(256) void k_wconv(
    const float* __restrict__ W1, const float* __restrict__ as1, const float* __restrict__ ad1,
    const float* __restrict__ W2, const float* __restrict__ W3,
    ushort_t* __restrict__ Wt2, ushort_t* __restrict__ Wt3, float* __restrict__ wsd,
    int* __restrict__ gCur, int nb) {
  int t = blockIdx.x * 256 + threadIdx.x;
  const int np = 128 * 128;
  const int n3 = np + 32 * 128;
  const int nl = n3 + 64;
  if (t < np) {
    int c = t / 128, k = t % 128;
    Wt2[t] = bfbits(W2[k * 128 + c]);
  } else if (t < n3) {
    int i = t - np;
    int c = i / 128, k = i % 128;
    Wt3[i] = bfbits(W3[k * 32 + c]);
  } else if (t < nl) {
    int i = t - n3;
    int h = (i >> 3) & 3, k = i & 7;
    const float* av = (i & 32) ? ad1 : as1;
    float acc = 0.f;
    for (int c = 0; c < 32; ++c) acc += W1[k * 128 + h * 32 + c] * av[h * 32 + c];
    wsd[i] = acc * LOG2E;
  } else if (t < nl + nb) {
    int i = t - nl;
    gCur[i] = i * CAPB;           // bucket cursor init
  }
}

// ---------------- layer-1 logits: als/ald = x @ (W1 @ a^T), 8-dim dots ----------------

__global__ __launch_bounds__(256) void k_logit1(const float* __restrict__ X,
    const float* __restrict__ wsd, float* __restrict__ als, float* __restrict__ ald, int n) {
  int i = blockIdx.x * 256 + threadIdx.x;
  if (i >= n) return;
  float4 xa = *(const float4*)&X[(size_t)i * 8];
  float4 xb = *(const float4*)&X[(size_t)i * 8 + 4];
  float x[8] = {xa.x, xa.y, xa.z, xa.w, xb.x, xb.y, xb.z, xb.w};
  float sv[4], dv[4];
  #pragma unroll
  for (int h = 0; h < 4; ++h) {
    float s = 0.f, d = 0.f;
    #pragma unroll
    for (int k = 0; k < 8; ++k) {
      s += x[k] * wsd[h * 8 + k];
      d += x[k] * wsd[32 + h * 8 + k];
    }
    sv[h] = s; dv[h] = d;
  }
  *(float4*)&als[(size_t)i * 4] = make_float4(sv[0], sv[1], sv[2], sv[3]);
  *(float4*)&ald[(size_t)i * 4] = make_float4(dv[0], dv[1], dv[2], dv[3]);
}

// ---------------- shared helper ----------------

__device__ __forceinline__ int sel4(int eg, int a, int b, int c, int d) {
  int r = (eg & 1) ? b : a;
  int r2 = (eg & 1) ? d : c;
  return (eg & 2) ? r2 : r;
}

// ---------------- layer-1 aggregate IN X-SPACE (linearity) ----------------

__global__ __launch_bounds__(256) void k_agg4x(const int* __restrict__ offs, const int* __restrict__ csr,
    const float* __restrict__ X, const float* __restrict__ als, const float* __restrict__ ald,
    const float* __restrict__ W1,
    const float* __restrict__ bias, const float* __restrict__ gam, const float* __restrict__ bet,
    const float* __restrict__ mu, const float* __restrict__ var,
    ushort_t* __restrict__ Xo, int n) {
  constexpr int UB = 6;
  constexpr int CAPW = 252;
  __shared__ int   s_idx[4][CAPW];
  __shared__ float s_exp[4][CAPW * 4];
  __shared__ float aggL[4][4][4][8];   // [wslot][node][head][dim]
  int wslot = threadIdx.x >> 6;
  int wid = (blockIdx.x * 256 + threadIdx.x) >> 6;
  int v0 = wid * 4;
  if (v0 >= n) return;                 // per-wave LDS; no barriers
  int lane = threadIdx.x & 63;

  int va = v0, vb = min(v0 + 1, n), vc = min(v0 + 2, n), vd = min(v0 + 3, n);
  int o0 = offs[va], o1 = offs[vb], o2 = offs[vc], o3 = offs[vd], o4 = offs[min(v0 + 4, n)];
  int d0 = o1 - o0, d1 = o2 - o1, d2 = o3 - o2, d3 = o4 - o3;

  int room = CAPW;
  int ms0 = min(d0, room); int mp0 = min((ms0 + UB - 1) / UB * UB, room); ms0 = min(ms0, mp0); room -= mp0;
  int ms1 = min(d1, room); int mp1 = min((ms1 + UB - 1) / UB * UB, room); ms1 = min(ms1, mp1); room -= mp1;
  int ms2 = min(d2, room); int mp2 = min((ms2 + UB - 1) / UB * UB, room); ms2 = min(ms2, mp2); room -= mp2;
  int ms3 = min(d3, room); int mp3 = min((ms3 + UB - 1) / UB * UB, room); ms3 = min(ms3, mp3);
  int p0 = 0, p1 = mp0, p2 = mp0 + mp1, p3 = mp0 + mp1 + mp2;

  int total = o4 - o0;
  for (int l = lane; l < total; l += 64) {
    int j = o0 + l;
    int nd = (j >= o1) + (j >= o2) + (j >= o3);
    int cbase = sel4(nd, o0 - p0, o1 - p1, o2 - p2, o3 - p3);
    int lim   = sel4(nd, p0 + ms0, p1 + ms1, p2 + ms2, p3 + ms3);
    int pos = j - cbase;
    if (pos < lim) {
      int s = csr[j];
      s_idx[wslot][pos] = s << 5;       // 8 floats = 32B per x row
      const float4 av = *(const float4*)&als[(size_t)s * 4];
      const float4 dv = *(const float4*)&ald[(size_t)(v0 + nd) * 4];
      float e0 = av.x + dv.x, e1 = av.y + dv.y, e2 = av.z + dv.z, e3 = av.w + dv.w;
      e0 = fmaxf(e0, 0.2f * e0); e1 = fmaxf(e1, 0.2f * e1);
      e2 = fmaxf(e2, 0.2f * e2); e3 = fmaxf(e3, 0.2f * e3);
      *(float4*)&s_exp[wslot][pos * 4] = make_float4(fexp2(e0), fexp2(e1), fexp2(e2), fexp2(e3));
    }
  }
  if (lane < 4 * UB) {
    int v = lane / UB, q = lane % UB;
    int msv = sel4(v, ms0, ms1, ms2, ms3);
    int mpv = sel4(v, mp0, mp1, mp2, mp3);
    int pv  = sel4(v, p0, p1, p2, p3);
    if (q < mpv - msv) {
      int pos = pv + msv + q;
      s_idx[wslot][pos] = 0;
      *(float4*)&s_exp[wslot][pos * 4] = make_float4(0.f, 0.f, 0.f, 0.f);
    }
  }

  int eg = lane >> 4;
  int fl = lane & 15;
  int myh = fl >> 2;
  int kp = fl & 3;
  int st  = sel4(eg, p0, p1, p2, p3);
  int mpv = sel4(eg, mp0, mp1, mp2, mp3);
  int msv = sel4(eg, ms0, ms1, ms2, ms3);
  int dgv = sel4(eg, d0, d1, d2, d3);
  int obv = sel4(eg, o0, o1, o2, o3);
  const char* xb = (const char*)X + kp * 8;

  f32x2 accx = (f32x2){0.f, 0.f};
  float den = 0.f;

  for (int j0 = 0; j0 < mpv; j0 += UB) {
    int ss[UB]; float ex[UB];
    #pragma unroll
    for (int u = 0; u < UB; ++u) {
      int pidx = st + j0 + u;
      ss[u] = s_idx[wslot][pidx];
      ex[u] = s_exp[wslot][pidx * 4 + myh];
    }
    f32x2 xv[UB];
    #pragma unroll
    for (int u = 0; u < UB; ++u)
      xv[u] = *(const f32x2*)(xb + (size_t)(unsigned)ss[u]);
    #pragma unroll
    for (int u = 0; u < UB; ++u)
      pkfma(accx, (f32x2){ex[u], ex[u]}, xv[u]);
    den += ((ex[0] + ex[1]) + (ex[2] + ex[3])) + (ex[4] + ex[5]);
  }
  if (dgv > msv) {
    float myald = ald[(size_t)(v0 + eg) * 4 + myh];
    for (int j = msv; j < dgv; ++j) {
      int s = csr[obv + j];
      float e = als[(size_t)s * 4 + myh] + myald;
      e = fmaxf(e, 0.2f * e);
      float exv = fexp2(e);
      den += exv;
      f32x2 xv = *(const f32x2*)(xb + ((size_t)s << 5));
      pkfma(accx, (f32x2){exv, exv}, xv);
    }
  }

  aggL[wslot][eg][myh][kp * 2]     = accx.x;
  aggL[wslot][eg][myh][kp * 2 + 1] = accx.y;

  int node = v0 + eg;
  if (node >= n) return;
  float inv = 1.f / (den + 1e-16f);
  float ax[8];
  *(float4*)&ax[0] = *(const float4*)&aggL[wslot][eg][myh][0];
  *(float4*)&ax[4] = *(const float4*)&aggL[wslot][eg][myh][4];

  int f0 = fl * 8;
  float acc[8];
  #pragma unroll
  for (int q = 0; q < 8; ++q) acc[q] = 0.f;
  #pragma unroll
  for (int k = 0; k < 8; ++k) {
    float4 w0 = *(const float4*)&W1[k * 128 + f0];
    float4 w1 = *(const float4*)&W1[k * 128 + f0 + 4];
    acc[0] += ax[k] * w0.x; acc[1] += ax[k] * w0.y;
    acc[2] += ax[k] * w0.z; acc[3] += ax[k] * w0.w;
    acc[4] += ax[k] * w1.x; acc[5] += ax[k] * w1.y;
    acc[6] += ax[k] * w1.z; acc[7] += ax[k] * w1.w;
  }

  float4 bi0 = *(const float4*)&bias[f0], bi1 = *(const float4*)&bias[f0 + 4];
  float4 mu0 = *(const float4*)&mu[f0],   mu1 = *(const float4*)&mu[f0 + 4];
  float4 va0 = *(const float4*)&var[f0],  va1 = *(const float4*)&var[f0 + 4];
  float4 ga0 = *(const float4*)&gam[f0],  ga1 = *(const float4*)&gam[f0 + 4];
  float4 be0 = *(const float4*)&bet[f0],  be1 = *(const float4*)&bet[f0 + 4];
  float bb[8] = {bi0.x, bi0.y, bi0.z, bi0.w, bi1.x, bi1.y, bi1.z, bi1.w};
  float mm[8] = {mu0.x, mu0.y, mu0.z, mu0.w, mu1.x, mu1.y, mu1.z, mu1.w};
  float vv[8] = {va0.x, va0.y, va0.z, va0.w, va1.x, va1.y, va1.z, va1.w};
  float gg[8] = {ga0.x, ga0.y, ga0.z, ga0.w, ga1.x, ga1.y, ga1.z, ga1.w};
  float ee[8] = {be0.x, be0.y, be0.z, be0.w, be1.x, be1.y, be1.z, be1.w};
  float ov[8];
  #pragma unroll
  for (int q = 0; q < 8; ++q) {
    float xo = acc[q] * inv + bb[q];
    xo = (xo - mm[q]) * rsqrtf(vv[q] + BN_EPS) * gg[q] + ee[q];
    ov[q] = (xo > 0.f) ? xo : (__expf(xo) - 1.f);
  }
  uint4 pk;
  pk.x = packbf2(ov[0], ov[1]); pk.y = packbf2(ov[2], ov[3]);
  pk.z = packbf2(ov[4], ov[5]); pk.w = packbf2(ov[6], ov[7]);
  *(uint4*)&Xo[(size_t)node * 128 + f0] = pk;
}

// ---------------- MFMA GEMM (K=128): H(bf16) = X(bf16) @ W(bf16), + logit dots ----------------

template<int FOUT>
__global__ __launch_bounds__(256) void k_gemm_mfma(
    const ushort_t* __restrict__ X, const ushort_t* __restrict__ Wt,
    const float* __restrict__ a_s, const float* __restrict__ a_d,
    ushort_t* __restrict__ Hout, float* __restrict__ als, float* __restrict__ ald, int n) {
  constexpr int HEADS = FOUT / 32;
  constexpr int BM = (FOUT == 128) ? 64 : 256;
  constexpr int LDC = FOUT + 8;
  __shared__ ushort_t Ct[BM * LDC];
  int tid = threadIdx.x;
  int w = tid >> 6, lane = tid & 63;
  int lo = lane & 15, hi = lane >> 4;
  int rowB = blockIdx.x * BM;
  int row0 = (FOUT == 128) ? rowB : rowB + w * 64;
  int nbase = (FOUT == 128) ? w * 32 : 0;
  int h = (FOUT == 128) ? w : 0;

  f32x4v acc[4][2];
  #pragma unroll
  for (int mf = 0; mf < 4; ++mf)
    #pragma unroll
    for (int nf = 0; nf < 2; ++nf) acc[mf][nf] = (f32x4v){0.f, 0.f, 0.f, 0.f};

  #pragma unroll
  for (int k0 = 0; k0 < 4; ++k0) {
    int kof = k0 * 32 + hi * 8;
    short8 b[2];
    #pragma unroll
    for (int nf = 0; nf < 2; ++nf) {
      int col = nbase + nf * 16 + lo;
      b[nf] = *(const short8*)&Wt[(size_t)col * 128 + kof];
    }
    short8 a[4];
    #pragma unroll
    for (int mf = 0; mf < 4; ++mf) {
      int row = row0 + mf * 16 + lo;
      row = min(row, n - 1);
      a[mf] = *(const short8*)&X[(size_t)row * 128 + kof];
    }
    #pragma unroll
    for (int mf = 0; mf < 4; ++mf)
      #pragma unroll
      for (int nf = 0; nf < 2; ++nf)
        acc[mf][nf] = __builtin_amdgcn_mfma_f32_16x16x32_bf16(a[mf], b[nf], acc[mf][nf], 0, 0, 0);
  }

  float as0 = a_s[h * 32 + lo] * LOG2E, as1 = a_s[h * 32 + 16 + lo] * LOG2E;
  float ad0 = a_d[h * 32 + lo] * LOG2E, ad1 = a_d[h * 32 + 16 + lo] * LOG2E;
  #pragma unroll
  for (int mf = 0; mf < 4; ++mf) {
    #pragma unroll
    for (int j = 0; j < 4; ++j) {
      float ps = acc[mf][0][j] * as0 + acc[mf][1][j] * as1;
      float pd = acc[mf][0][j] * ad0 + acc[mf][1][j] * ad1;
      #pragma unroll
      for (int m = 1; m < 16; m <<= 1) {
        ps += __shfl_xor(ps, m, 64);
        pd += __shfl_xor(pd, m, 64);
      }
      if (lo == 0) {
        int row = row0 + mf * 16 + hi * 4 + j;
        if (row < n) {
          als[(size_t)row * HEADS + h] = ps;
          ald[(size_t)row * HEADS + h] = pd;
        }
      }
    }
  }

  #pragma unroll
  for (int mf = 0; mf < 4; ++mf) {
    int rL = ((FOUT == 128) ? 0 : w * 64) + mf * 16 + hi * 4;
    #pragma unroll
    for (int nf = 0; nf < 2; ++nf) {
      int cL = nbase + nf * 16 + lo;
      #pragma unroll
      for (int j = 0; j < 4; ++j)
        Ct[(rL + j) * LDC + cL] = bfbits(acc[mf][nf][j]);
    }
  }
  __syncthreads();
  constexpr int CPR = FOUT / 8;
  #pragma unroll
  for (int i = 0; i < (BM * CPR) / 256; ++i) {
    int idx = tid + i * 256;
    int r = idx / CPR, c = idx % CPR;
    int grow = rowB + r;
    if (grow < n)
      *(uint4*)&Hout[(size_t)grow * FOUT + c * 8] = *(const uint4*)&Ct[r * LDC + c * 8];
  }
}

// ---------------- agg for HEADS=4/FEAT=128 (layer 2): 4 nodes/wave, 16 lanes/node ----------------

__global__ __launch_bounds__(256) void k_agg4(const int* __restrict__ offs, const int* __restrict__ csr,
    const ushort_t* __restrict__ Hb, const float* __restrict__ als, const float* __restrict__ ald,
    const float* __restrict__ bias, const float* __restrict__ gam, const float* __restrict__ bet,
    const float* __restrict__ mu, const float* __restrict__ var,
    ushort_t* __restrict__ Xo, int n) {
  constexpr int UB = 6;
  constexpr int CAPW = 252;
  __shared__ int   s_idx[4][CAPW];
  __shared__ float s_exp[4][CAPW * 4];
  int wslot = threadIdx.x >> 6;
  int wid = (blockIdx.x * 256 + threadIdx.x) >> 6;
  int v0 = wid * 4;
  if (v0 >= n) return;
  int lane = threadIdx.x & 63;

  int va = v0, vb = min(v0 + 1, n), vc = min(v0 + 2, n), vd = min(v0 + 3, n);
  int o0 = offs[va], o1 = offs[vb], o2 = offs[vc], o3 = offs[vd], o4 = offs[min(v0 + 4, n)];
  int d0 = o1 - o0, d1 = o2 - o1, d2 = o3 - o2, d3 = o4 - o3;

  int room = CAPW;
  int ms0 = min(d0, room); int mp0 = min((ms0 + UB - 1) / UB * UB, room); ms0 = min(ms0, mp0); room -= mp0;
  int ms1 = min(d1, room); int mp1 = min((ms1 + UB - 1) / UB * UB, room); ms1 = min(ms1, mp1); room -= mp1;
  int ms2 = min(d2, room); int mp2 = min((ms2 + UB - 1) / UB * UB, room); ms2 = min(ms2, mp2); room -= mp2;
  int ms3 = min(d3, room); int mp3 = min((ms3 + UB - 1) / UB * UB, room); ms3 = min(ms3, mp3);
  int p0 = 0, p1 = mp0, p2 = mp0 + mp1, p3 = mp0 + mp1 + mp2;

  int total = o4 - o0;
  for (int l = lane; l < total; l += 64) {
    int j = o0 + l;
    int nd = (j >= o1) + (j >= o2) + (j >= o3);
    int cbase = sel4(nd, o0 - p0, o1 - p1, o2 - p2, o3 - p3);
    int lim   = sel4(nd, p0 + ms0, p1 + ms1, p2 + ms2, p3 + ms3);
    int pos = j - cbase;
    if (pos < lim) {
      int s = csr[j];
      s_idx[wslot][pos] = s << 8;
      const float4 av = *(const float4*)&als[(size_t)s * 4];
      const float4 dv = *(const float4*)&ald[(size_t)(v0 + nd) * 4];
      float e0 = av.x + dv.x, e1 = av.y + dv.y, e2 = av.z + dv.z, e3 = av.w + dv.w;
      e0 = fmaxf(e0, 0.2f * e0); e1 = fmaxf(e1, 0.2f * e1);
      e2 = fmaxf(e2, 0.2f * e2); e3 = fmaxf(e3, 0.2f * e3);
      *(float4*)&s_exp[wslot][pos * 4] = make_float4(fexp2(e0), fexp2(e1), fexp2(e2), fexp2(e3));
    }
  }
  if (lane < 4 * UB) {
    int v = lane / UB, q = lane % UB;
    int msv = sel4(v, ms0, ms1, ms2, ms3);
    int mpv = sel4(v, mp0, mp1, mp2, mp3);
    int pv  = sel4(v, p0, p1, p2, p3);
    if (q < mpv - msv) {
      int pos = pv + msv + q;
      s_idx[wslot][pos] = 0;
      *(float4*)&s_exp[wslot][pos * 4] = make_float4(0.f, 0.f, 0.f, 0.f);
    }
  }

  int eg = lane >> 4;
  int fl = lane & 15;
  int f0 = fl * 8;
  int myh = f0 >> 5;
  int st  = sel4(eg, p0, p1, p2, p3);
  int mpv = sel4(eg, mp0, mp1, mp2, mp3);
  int msv = sel4(eg, ms0, ms1, ms2, ms3);
  int dgv = sel4(eg, d0, d1, d2, d3);
  int obv = sel4(eg, o0, o1, o2, o3);
  const char* hb = (const char*)Hb + f0 * 2;

  f32x2 acc2[4];
  #pragma unroll
  for (int q = 0; q < 4; ++q) acc2[q] = (f32x2){0.f, 0.f};
  float den = 0.f;

  for (int j0 = 0; j0 < mpv; j0 += UB) {
    int ss[UB]; float ex[UB];
    #pragma unroll
    for (int u = 0; u < UB; ++u) {
      int pidx = st + j0 + u;
      ss[u] = s_idx[wslot][pidx];
      ex[u] = s_exp[wslot][pidx * 4 + myh];
    }
    uint4 pv[UB];
    #pragma unroll
    for (int u = 0; u < UB; ++u)
      pv[u] = *(const uint4*)(hb + (size_t)(unsigned)ss[u]);
    #pragma unroll
    for (int u = 0; u < UB; ++u) {
      f32x2 e2v = (f32x2){ex[u], ex[u]};
      pkfma(acc2[0], e2v, (f32x2){blo(pv[u].x), bhi(pv[u].x)});
      pkfma(acc2[1], e2v, (f32x2){blo(pv[u].y), bhi(pv[u].y)});
      pkfma(acc2[2], e2v, (f32x2){blo(pv[u].z), bhi(pv[u].z)});
      pkfma(acc2[3], e2v, (f32x2){blo(pv[u].w), bhi(pv[u].w)});
    }
    den += ((ex[0] + ex[1]) + (ex[2] + ex[3])) + (ex[4] + ex[5]);
  }
  if (dgv > msv) {
    float myald = ald[(size_t)(v0 + eg) * 4 + myh];
    for (int j = msv; j < dgv; ++j) {
      int s = csr[obv + j];
      float e = als[(size_t)s * 4 + myh] + myald;
      e = fmaxf(e, 0.2f * e);
      float exv = fexp2(e);
      den += exv;
      uint4 pv = *(const uint4*)(Hb + (size_t)s * 128 + f0);
      f32x2 e2v = (f32x2){exv, exv};
      pkfma(acc2[0], e2v, (f32x2){blo(pv.x), bhi(pv.x)});
      pkfma(acc2[1], e2v, (f32x2){blo(pv.y), bhi(pv.y)});
      pkfma(acc2[2], e2v, (f32x2){blo(pv.z), bhi(pv.z)});
      pkfma(acc2[3], e2v, (f32x2){blo(pv.w), bhi(pv.w)});
    }
  }

  int node = v0 + eg;
  if (node >= n) return;
  float acc[8] = {acc2[0].x, acc2[0].y, acc2[1].x, acc2[1].y,
                  acc2[2].x, acc2[2].y, acc2[3].x, acc2[3].y};
  float inv = 1.f / (den + 1e-16f);
  float4 bi0 = *(const float4*)&bias[f0], bi1 = *(const float4*)&bias[f0 + 4];
  float4 mu0 = *(const float4*)&mu[f0],   mu1 = *(const float4*)&mu[f0 + 4];
  float4 va0 = *(const float4*)&var[f0],  va1 = *(const float4*)&var[f0 + 4];
  float4 ga0 = *(const float4*)&gam[f0],  ga1 = *(const float4*)&gam[f0 + 4];
  float4 be0 = *(const float4*)&bet[f0],  be1 = *(const float4*)&bet[f0 + 4];
  float bb[8] = {bi0.x, bi0.y, bi0.z, bi0.w, bi1.x, bi1.y, bi1.z, bi1.w};
  float mm[8] = {mu0.x, mu0.y, mu0.z, mu0.w, mu1.x, mu1.y, mu1.z, mu1.w};
  float vv[8] = {va0.x, va0.y, va0.z, va0.w, va1.x, va1.y, va1.z, va1.w};
  float gg[8] = {ga0.x, ga0.y, ga0.z, ga0.w, ga1.x, ga1.y, ga1.z, ga1.w};
  float ee[8] = {be0.x, be0.y, be0.z, be0.w, be1.x, be1.y, be1.z, be1.w};
  float ov[8];
  #pragma unroll
  for (int q = 0; q < 8; ++q) {
    float xo = acc[q] * inv + bb[q];
    xo = (xo - mm[q]) * rsqrtf(vv[q] + BN_EPS) * gg[q] + ee[q];
    ov[q] = (xo > 0.f) ? xo : (__expf(xo) - 1.f);
  }
  uint4 pk;
  pk.x = packbf2(ov[0], ov[1]); pk.y = packbf2(ov[2], ov[3]);
  pk.z = packbf2(ov[4], ov[5]); pk.w = packbf2(ov[6], ov[7]);
  *(uint4*)&Xo[(size_t)node * 128 + f0] = pk;
}

// ---------------- agg for HEADS=1/FEAT=32 (layer 3): f32 out (feeds classifier) ----------------

__global__ __launch_bounds__(256) void k_agg1(const int* __restrict__ offs, const int* __restrict__ csr,
    const ushort_t* __restrict__ Hb, const float* __restrict__ als, const float* __restrict__ ald,
    const float* __restrict__ bias, const float* __restrict__ gam, const float* __restrict__ bet,
    const float* __restrict__ mu, const float* __restrict__ var,
    float* __restrict__ Xo, int n) {
  constexpr int LPF = 4;
  constexpr int EPW = 16;
  constexpr int UB = 2;
  constexpr int STEP = 32;
  constexpr int CAP = 128;
  __shared__ int   s_idx[4][CAP];
  __shared__ float s_exp[4][CAP];
  int wslot = threadIdx.x >> 6;
  int wv = (blockIdx.x * 256 + threadIdx.x) >> 6;
  if (wv >= n) return;
  int lane = threadIdx.x & 63;
  int rs = offs[wv];
  int deg = offs[wv + 1] - rs;
  int dstage = deg < CAP ? deg : CAP;
  int dpad = ((dstage + STEP - 1) / STEP) * STEP;
  float ald0 = ald[wv];

  for (int j = lane; j < dpad; j += 64) {
    if (j < dstage) {
      int s = csr[rs + j];
      s_idx[wslot][j] = s << 6;
      float e = als[s] + ald0;
      e = fmaxf(e, 0.2f * e);
      s_exp[wslot][j] = fexp2(e);
    } else {
      s_idx[wslot][j] = 0;
      s_exp[wslot][j] = 0.f;
    }
  }

  int fl = lane % LPF;
  int eg = lane / LPF;
  int f0 = fl * 8;
  const char* hb = (const char*)Hb + f0 * 2;

  f32x2 acc2[4];
  #pragma unroll
  for (int q = 0; q < 4; ++q) acc2[q] = (f32x2){0.f, 0.f};
  float den = 0.f;

  for (int j0 = eg; j0 < dpad; j0 += STEP) {
    int ss[UB]; float ex[UB];
    #pragma unroll
    for (int u = 0; u < UB; ++u) {
      int j = j0 + u * EPW;
      ss[u] = s_idx[wslot][j];
      ex[u] = s_exp[wslot][j];
    }
    uint4 pv[UB];
    #pragma unroll
    for (int u = 0; u < UB; ++u)
      pv[u] = *(const uint4*)(hb + (size_t)(unsigned)ss[u]);
    #pragma unroll
    for (int u = 0; u < UB; ++u) {
      f32x2 e2v = (f32x2){ex[u], ex[u]};
      pkfma(acc2[0], e2v, (f32x2){blo(pv[u].x), bhi(pv[u].x)});
      pkfma(acc2[1], e2v, (f32x2){blo(pv[u].y), bhi(pv[u].y)});
      pkfma(acc2[2], e2v, (f32x2){blo(pv[u].z), bhi(pv[u].z)});
      pkfma(acc2[3], e2v, (f32x2){blo(pv[u].w), bhi(pv[u].w)});
      den += ex[u];
    }
  }
  if (deg > CAP) {
    for (int j = CAP + eg; j < deg; j += EPW) {
      int s = csr[rs + j];
      float e = als[s] + ald0;
      e = fmaxf(e, 0.2f * e);
      float exv = fexp2(e);
      den += exv;
      uint4 pv = *(const uint4*)(Hb + (size_t)s * 32 + f0);
      f32x2 e2v = (f32x2){exv, exv};
      pkfma(acc2[0], e2v, (f32x2){blo(pv.x), bhi(pv.x)});
      pkfma(acc2[1], e2v, (f32x2){blo(pv.y), bhi(pv.y)});
      pkfma(acc2[2], e2v, (f32x2){blo(pv.z), bhi(pv.z)});
      pkfma(acc2[3], e2v, (f32x2){blo(pv.w), bhi(pv.w)});
    }
  }

  float acc[8] = {acc2[0].x, acc2[0].y, acc2[1].x, acc2[1].y,
                  acc2[2].x, acc2[2].y, acc2[3].x, acc2[3].y};
  #pragma unroll
  for (int off = 32; off >= LPF; off >>= 1) {
    den += __shfl_xor(den, off, 64);
    #pragma unroll
    for (int q = 0; q < 8; ++q) acc[q] += __shfl_xor(acc[q], off, 64);
  }
  float inv = 1.f / (den + 1e-16f);

  if (lane < LPF) {
    float ov[8];
    #pragma unroll
    for (int q = 0; q < 8; ++q) {
      int f = f0 + q;
      float xo = acc[q] * inv + bias[f];
      xo = (xo - mu[f]) * rsqrtf(var[f] + BN_EPS) * gam[f] + bet[f];
      ov[q] = (xo > 0.f) ? xo : (__expf(xo) - 1.f);
    }
    *(float4*)(Xo + (size_t)wv * 32 + f0)     = make_float4(ov[0], ov[1], ov[2], ov[3]);
    *(float4*)(Xo + (size_t)wv * 32 + f0 + 4) = make_float4(ov[4], ov[5], ov[6], ov[7]);
  }
}

// ---------------- classifier ----------------

__global__ __launch_bounds__(256) void k_cls(const float* __restrict__ X3,
    const float* __restrict__ cW1, const float* __restrict__ cb1,
    const float* __restrict__ cW2, const float* __restrict__ cb2,
    float* __restrict__ out, int n) {
  int i = blockIdx.x * 256 + threadIdx.x;
  if (i >= n) return;
  float x[32];
  #pragma unroll
  for (int k = 0; k < 32; k += 4) {
    float4 v = *(const float4*)&X3[(size_t)i * 32 + k];
    x[k] = v.x; x[k + 1] = v.y; x[k + 2] = v.z; x[k + 3] = v.w;
  }
  float o = cb2[0];
  #pragma unroll
  for (int j = 0; j < 16; ++j) {
    float hs = cb1[j];
    #pragma unroll
    for (int k = 0; k < 32; ++k) hs += x[k] * cW1[k * 16 + j];
    hs = fmaxf(hs, 0.f);
    o += hs * cW2[j];
  }
  out[i] = 1.f / (1.f + __expf(-o));
}

// ---------------- host ----------------

static inline size_t align256(size_t x) { return (x + 255) & ~(size_t)255; }

extern "C" void kernel_launch(void* const* d_in, const int* in_sizes, int n_in,
                              void* d_out, int out_size, void* d_ws, size_t ws_size,
                              hipStream_t stream) {
  const float* x   = (const float*)d_in[0];
  const int*   ei  = (const int*)d_in[1];
  const float* W1  = (const float*)d_in[2];
  const float* as1 = (const float*)d_in[3];
  const float* ad1 = (const float*)d_in[4];
  const float* b1  = (const float*)d_in[5];
  const float* g1  = (const float*)d_in[6];
  const float* be1 = (const float*)d_in[7];
  const float* m1  = (const float*)d_in[8];
  const float* v1  = (const float*)d_in[9];
  const float* W2  = (const float*)d_in[10];
  const float* as2 = (const float*)d_in[11];
  const float* ad2 = (const float*)d_in[12];
  const float* b2  = (const float*)d_in[13];
  const float* g2  = (const float*)d_in[14];
  const float* be2 = (const float*)d_in[15];
  const float* m2  = (const float*)d_in[16];
  const float* v2  = (const float*)d_in[17];
  const float* W3  = (const float*)d_in[18];
  const float* as3 = (const float*)d_in[19];
  const float* ad3 = (const float*)d_in[20];
  const float* b3  = (const float*)d_in[21];
  const float* g3  = (const float*)d_in[22];
  const float* be3 = (const float*)d_in[23];
  const float* m3  = (const float*)d_in[24];
  const float* v3  = (const float*)d_in[25];
  const float* cW1 = (const float*)d_in[26];
  const float* cb1 = (const float*)d_in[27];
  const float* cW2 = (const float*)d_in[28];
  const float* cb2 = (const float*)d_in[29];

  const int n = in_sizes[0] / 8;
  const int E = in_sizes[1] / 2;
  const int etot = E + n;
  const int nb = (n + 255) / 256;

  // workspace carve
  char* p = (char*)d_ws;
  int* offs   = (int*)p;  p += align256((size_t)(n + 1) * 4);
  int* csr    = (int*)p;  p += align256((size_t)etot * 4);
  int* gCur   = (int*)p;  p += align256(1024);
  unsigned* bkt = (unsigned*)p; p += align256((size_t)nb * CAPB * 4);
  float* als  = (float*)p; p += align256((size_t)n * 4 * 4);
  float* ald  = (float*)p; p += align256((size_t)n * 4 * 4);
  ushort_t* bufH = (ushort_t*)p; p += align256((size_t)n * 128 * 2);  // bf16 H (layers 2,3)
  ushort_t* bufX = (ushort_t*)p; p += align256((size_t)n * 128 * 2);  // bf16 layer output
  float* x3f  = (float*)p; p += align256((size_t)n * 32 * 4);          // f32 layer-3 output
  ushort_t* wt2 = (ushort_t*)p; p += align256(128 * 128 * 2);
  ushort_t* wt3 = (ushort_t*)p; p += align256(32 * 128 * 2);
  float* wsd  = (float*)p; p += align256(64 * 4);                      // layer-1 logit vecs

  // preconvert + gCur init, then CSR build
  k_wconv<<<82, 256, 0, stream>>>(W1, as1, ad1, W2, W3, wt2, wt3, wsd, gCur, nb);
  k_bucket<<<(etot + 1023) / 1024, 256, 0, stream>>>(ei, E, etot, bkt, gCur, nb);
  k_csr<<<nb, 256, 0, stream>>>(bkt, gCur, csr, offs, n, nb, etot);

  const int ga4 = (n + 15) / 16;   // 16 nodes/block (4 waves x 4 nodes)
  const int ga1 = (n + 3) / 4;     // 4 nodes/block

  // layer 1: logits + x-space aggregate (W1 applied post-aggregation; linearity)
  k_logit1<<<(n + 255) / 256, 256, 0, stream>>>(x, wsd, als, ald, n);
  k_agg4x<<<ga4, 256, 0, stream>>>(offs, csr, x, als, ald, W1, b1, g1, be1, m1, v1, bufX, n);

  // layer 2: MFMA GEMM + agg
  k_gemm_mfma<128><<<(n + 63) / 64, 256, 0, stream>>>(bufX, wt2, as2, ad2, bufH, als, ald, n);
  k_agg4<<<ga4, 256, 0, stream>>>(offs, csr, bufH, als, ald, b2, g2, be2, m2, v2, bufX, n);

  // layer 3: MFMA GEMM + agg
  k_gemm_mfma<32><<<(n + 255) / 256, 256, 0, stream>>>(bufX, wt3, as3, ad3, bufH, als, ald, n);
  k_agg1<<<ga1, 256, 0, stream>>>(offs, csr, bufH, als, ald, b3, g3, be3, m3, v3, x3f, n);

  // classifier
  k_cls<<<(n + 255) / 256, 256, 0, stream>>>(x3f, cW1, cb1, cW2, cb2, (float*)d_out, n);
}